// Round 3
// baseline (3791.641 us; speedup 1.0000x reference)
//
#include <hip/hip_runtime.h>
#include <hip/hip_bf16.h>

#define BB 64
#define SS 128
#define LSRC 256
#define HH 512
#define NHEAD 8
#define HDIM 64
#define VV 8000
#define M1 (BB*SS)     // 8192
#define M2 (BB*LSRC)   // 16384

typedef unsigned short u16;
typedef __attribute__((ext_vector_type(8))) short bf16x8;
typedef __attribute__((ext_vector_type(4))) float f32x4;

__device__ __forceinline__ float b2f(u16 u){
    unsigned int x = ((unsigned int)u) << 16;
    return __uint_as_float(x);
}
__device__ __forceinline__ u16 f2b(float f){
    unsigned int x = __float_as_uint(f);
    x = x + 0x7fffu + ((x >> 16) & 1u);
    return (u16)(x >> 16);
}

// ---------------- dtype probe: bf16 data never has exp>=0x80 (|x|>=2); f32 low-mantissa halves do ~50%
__global__ __launch_bounds__(256) void k_probe(const u16* __restrict__ emb, int* __restrict__ flag){
    __shared__ int tot;
    if (threadIdx.x == 0) tot = 0;
    __syncthreads();
    int cnt = 0;
    #pragma unroll
    for (int i = 0; i < 32; i++){
        u16 u = emb[threadIdx.x * 32 + i];
        cnt += (((u >> 7) & 0xFF) >= 0x80);
    }
    #pragma unroll
    for (int off = 1; off < 64; off <<= 1) cnt += __shfl_xor(cnt, off);
    if ((threadIdx.x & 63) == 0) atomicAdd(&tot, cnt);
    __syncthreads();
    if (threadIdx.x == 0) *flag = (tot > 100) ? 1 : 0;
}

// ---------------- input normalization: f32->bf16 convert, or bf16 passthrough copy ----------------
__global__ __launch_bounds__(256) void k_convert(const void* __restrict__ src, u16* __restrict__ dst,
                                                 const int* __restrict__ flag, long n8){
    long i = (long)blockIdx.x * 256 + threadIdx.x;
    if (i >= n8) return;
    if (*flag){
        const float4* s = (const float4*)src;
        float4 a = s[i*2], b = s[i*2+1];
        u16 o[8] = { f2b(a.x), f2b(a.y), f2b(a.z), f2b(a.w), f2b(b.x), f2b(b.y), f2b(b.z), f2b(b.w) };
        *(uint4*)(dst + i*8) = *(const uint4*)o;
    } else {
        *(uint4*)(dst + i*8) = ((const uint4*)src)[i];
    }
}

// ---------------- embed + query_input ----------------
__global__ __launch_bounds__(256) void k_embed(const int* __restrict__ pc,
    const u16* __restrict__ emb, const u16* __restrict__ h0,
    u16* __restrict__ gruin, u16* __restrict__ qin)
{
    int c = blockIdx.x * 256 + threadIdx.x;   // 524288 chunks of 8 elems
    int row = c >> 6;
    int kc = (c & 63) << 3;
    int b = row >> 7;
    int tok = pc[row];
    uint4 e = *(const uint4*)(emb + (long)tok * HH + kc);
    *(uint4*)(gruin + (long)row * (2*HH) + kc) = e;   // char_emb -> gru_input[:, :512]
    uint4 hv = *(const uint4*)(h0 + b * HH + kc);
    const u16* ep = (const u16*)&e;
    const u16* hp = (const u16*)&hv;
    u16 q[8];
    #pragma unroll
    for (int j = 0; j < 8; j++) q[j] = f2b(b2f(ep[j]) + b2f(hp[j]));
    *(uint4*)(qin + (long)row * HH + kc) = *(const uint4*)q;
}

__global__ __launch_bounds__(256) void k_h0(const u16* __restrict__ h0, float* __restrict__ hf){
    int i = blockIdx.x * 256 + threadIdx.x;   // grid 128 -> 32768
    hf[i] = b2f(h0[i]);
}

// ---------------- generic bf16 MFMA GEMM: C[M,N] = A[M,K] * W[N,K]^T + bias ----------------
__global__ __launch_bounds__(256) void gemm_bt(
    const u16* __restrict__ A, int lda,
    const u16* __restrict__ W, int ldw,
    const u16* __restrict__ bias,
    u16* __restrict__ Cb, float* __restrict__ Cf, int ldc,
    int N, int K)
{
    __shared__ u16 As[128*64];
    __shared__ u16 Bs[128*64];
    const int tid = threadIdx.x;
    const int wave = tid >> 6, lane = tid & 63;
    const int m0 = blockIdx.x * 128, n0 = blockIdx.y * 128;
    const int wm = (wave & 1) * 64, wn = (wave >> 1) * 64;
    const int lm = lane & 15, lq = lane >> 4;
    f32x4 acc[4][4];
    #pragma unroll
    for (int i = 0; i < 4; i++)
        #pragma unroll
        for (int j = 0; j < 4; j++) acc[i][j] = (f32x4){0.f,0.f,0.f,0.f};

    for (int k0 = 0; k0 < K; k0 += 64) {
        #pragma unroll
        for (int i = 0; i < 4; i++) {
            int chunk = i*256 + tid;               // 1024 chunks of 8 bf16
            int row = chunk >> 3, kc = (chunk & 7) << 3;
            *(uint4*)(As + chunk*8) = *(const uint4*)(A + (long)(m0+row)*lda + k0 + kc);
            int brow = n0 + row; if (brow >= N) brow = N - 1;   // clamp for N=8000 tail
            *(uint4*)(Bs + chunk*8) = *(const uint4*)(W + (long)brow*ldw + k0 + kc);
        }
        __syncthreads();
        #pragma unroll
        for (int kk = 0; kk < 64; kk += 32) {
            bf16x8 af[4], bfr[4];
            #pragma unroll
            for (int i = 0; i < 4; i++){
                af[i]  = *(const bf16x8*)(As + (wm + i*16 + lm)*64 + kk + lq*8);
                bfr[i] = *(const bf16x8*)(Bs + (wn + i*16 + lm)*64 + kk + lq*8);
            }
            #pragma unroll
            for (int mi = 0; mi < 4; mi++)
                #pragma unroll
                for (int ni = 0; ni < 4; ni++)
                    acc[mi][ni] = __builtin_amdgcn_mfma_f32_16x16x32_bf16(af[mi], bfr[ni], acc[mi][ni], 0, 0, 0);
        }
        __syncthreads();
    }
    // C/D layout: col = lane&15, row = (lane>>4)*4 + reg
    #pragma unroll
    for (int ni = 0; ni < 4; ni++){
        int n = n0 + wn + ni*16 + lm;
        if (n >= N) continue;
        float bv = bias ? b2f(bias[n]) : 0.f;
        #pragma unroll
        for (int mi = 0; mi < 4; mi++){
            #pragma unroll
            for (int r = 0; r < 4; r++){
                int m = m0 + wm + mi*16 + lq*4 + r;
                float v = acc[mi][ni][r] + bv;
                if (Cf) Cf[(long)m*ldc + n] = v;
                else    Cb[(long)m*ldc + n] = f2b(v);
            }
        }
    }
}

// ---------------- fused attention core: scores -> softmax -> ctx, per (b, head, 32-row s-tile) ----
__global__ __launch_bounds__(256) void k_attn(const u16* __restrict__ Qb,
    const u16* __restrict__ Kb, const u16* __restrict__ Vb, u16* __restrict__ ctxb)
{
    __shared__ u16 Ks[LSRC*72];
    __shared__ u16 Vs[LSRC*72];
    __shared__ u16 Qs[32*72];
    int bid = blockIdx.x;
    int st = bid & 3, h = (bid >> 2) & 7, b = bid >> 5;
    int tid = threadIdx.x;
    long kvbase = (long)b*LSRC*HH + h*HDIM;
    #pragma unroll
    for (int i = 0; i < 8; i++){
        int c = i*256 + tid;
        int r = c >> 3, kc = (c & 7) << 3;
        *(uint4*)(Ks + r*72 + kc) = *(const uint4*)(Kb + kvbase + (long)r*HH + kc);
        *(uint4*)(Vs + r*72 + kc) = *(const uint4*)(Vb + kvbase + (long)r*HH + kc);
    }
    {   int r = tid >> 3, kc = (tid & 7) << 3;
        *(uint4*)(Qs + r*72 + kc) = *(const uint4*)(Qb + (long)(b*SS + st*32 + r)*HH + h*HDIM + kc);
    }
    __syncthreads();
    int sl = tid >> 3, sub = tid & 7;
    float qv[64];
    #pragma unroll
    for (int k = 0; k < 64; k++) qv[k] = b2f(Qs[sl*72 + k]);
    float p[32];
    float mx = -1e30f;
    #pragma unroll
    for (int i = 0; i < 32; i++){
        int l = sub + i*8;
        float d = 0.f;
        #pragma unroll
        for (int k = 0; k < 64; k += 4){
            uint2 kw = *(const uint2*)(Ks + l*72 + k);
            const u16* kp = (const u16*)&kw;
            d += qv[k]*b2f(kp[0]) + qv[k+1]*b2f(kp[1]) + qv[k+2]*b2f(kp[2]) + qv[k+3]*b2f(kp[3]);
        }
        p[i] = d * 0.125f;
        mx = fmaxf(mx, p[i]);
    }
    mx = fmaxf(mx, __shfl_xor(mx, 1));
    mx = fmaxf(mx, __shfl_xor(mx, 2));
    mx = fmaxf(mx, __shfl_xor(mx, 4));
    float sum = 0.f;
    #pragma unroll
    for (int i = 0; i < 32; i++){ p[i] = __expf(p[i] - mx); sum += p[i]; }
    sum += __shfl_xor(sum, 1); sum += __shfl_xor(sum, 2); sum += __shfl_xor(sum, 4);
    float inv = 1.f / sum;
    float acc[64];
    #pragma unroll
    for (int c = 0; c < 64; c++) acc[c] = 0.f;
    #pragma unroll
    for (int i = 0; i < 32; i++){
        int l = sub + i*8;
        float w = p[i];
        #pragma unroll
        for (int c = 0; c < 64; c += 4){
            uint2 vw = *(const uint2*)(Vs + l*72 + c);
            const u16* vp = (const u16*)&vw;
            acc[c]   += w * b2f(vp[0]);
            acc[c+1] += w * b2f(vp[1]);
            acc[c+2] += w * b2f(vp[2]);
            acc[c+3] += w * b2f(vp[3]);
        }
    }
    u16 ob[8];
    #pragma unroll
    for (int c = 0; c < 64; c++){
        float v = acc[c];
        v += __shfl_xor(v, 1); v += __shfl_xor(v, 2); v += __shfl_xor(v, 4);
        v *= inv;
        if ((c >> 3) == sub) ob[c & 7] = f2b(v);
    }
    long obase = (long)(b*SS + st*32 + sl)*HH + h*HDIM + sub*8;
    *(uint4*)(ctxb + obase) = *(const uint4*)ob;
}

// ---------------- one GRU time step ----------------
__global__ __launch_bounds__(256) void k_gru_step(
    const float* __restrict__ gi, const u16* __restrict__ whh, const u16* __restrict__ bhh,
    const float* __restrict__ hprev, float* __restrict__ hnext, u16* __restrict__ hout, int s)
{
    __shared__ u16 hs[64*536];
    int tid = threadIdx.x;
    int j0 = blockIdx.x * 16;
    #pragma unroll
    for (int i = 0; i < 32; i++){
        int c = i*256 + tid;
        int b = c >> 7, kc = (c & 127) << 2;
        float4 v = *(const float4*)(hprev + b*HH + kc);
        u16 u[4] = { f2b(v.x), f2b(v.y), f2b(v.z), f2b(v.w) };
        *(uint2*)(hs + b*536 + kc) = *(const uint2*)u;
    }
    __syncthreads();
    int wave = tid >> 6, lane = tid & 63;
    int lm = lane & 15, lq = lane >> 4;
    f32x4 acc[3];
    acc[0] = (f32x4){0.f,0.f,0.f,0.f};
    acc[1] = acc[0]; acc[2] = acc[0];
    int brow = wave*16 + lm;
    #pragma unroll
    for (int k0 = 0; k0 < 512; k0 += 32){
        bf16x8 a = *(const bf16x8*)(hs + brow*536 + k0 + lq*8);
        #pragma unroll
        for (int g = 0; g < 3; g++){
            bf16x8 wf = *(const bf16x8*)(whh + (long)(g*512 + j0 + lm)*HH + k0 + lq*8);
            acc[g] = __builtin_amdgcn_mfma_f32_16x16x32_bf16(a, wf, acc[g], 0, 0, 0);
        }
    }
    int j = j0 + lm;
    float br = b2f(bhh[j]), bz = b2f(bhh[512+j]), bn = b2f(bhh[1024+j]);
    #pragma unroll
    for (int r = 0; r < 4; r++){
        int b = wave*16 + lq*4 + r;
        long gbase = (long)(b*SS + s)*1536;
        float i_r = gi[gbase + j];
        float i_z = gi[gbase + 512 + j];
        float i_n = gi[gbase + 1024 + j];
        float hp = hprev[b*HH + j];
        float rg = 1.f/(1.f + __expf(-(i_r + acc[0][r] + br)));
        float zg = 1.f/(1.f + __expf(-(i_z + acc[1][r] + bz)));
        float ng = tanhf(i_n + rg*(acc[2][r] + bn));
        float hv = (1.f - zg)*ng + zg*hp;
        hnext[b*HH + j] = hv;
        hout[(long)(b*SS + s)*HH + j] = f2b(hv);
    }
}

// ---------------- row softmax over V=8000: ws bf16 logits -> d_out (bf16 or f32 per flag) -------
__global__ __launch_bounds__(256) void k_softmax(const u16* __restrict__ logits, void* __restrict__ out,
                                                 const int* __restrict__ flag)
{
    __shared__ float red[4];
    __shared__ float red2[4];
    long row = blockIdx.x;
    const u16* p = logits + row*VV;
    int tid = threadIdx.x, wave = tid >> 6, lane = tid & 63;
    float v[32];
    float mx = -1e30f;
    #pragma unroll
    for (int i = 0; i < 32; i++){
        int c = tid + i*256;
        v[i] = (c < VV) ? b2f(p[c]) : -1e30f;
        mx = fmaxf(mx, v[i]);
    }
    #pragma unroll
    for (int off = 1; off < 64; off <<= 1) mx = fmaxf(mx, __shfl_xor(mx, off));
    if (lane == 0) red[wave] = mx;
    __syncthreads();
    mx = fmaxf(fmaxf(red[0], red[1]), fmaxf(red[2], red[3]));
    float sum = 0.f;
    #pragma unroll
    for (int i = 0; i < 32; i++){
        int c = tid + i*256;
        if (c < VV){ v[i] = __expf(v[i] - mx); sum += v[i]; }
    }
    #pragma unroll
    for (int off = 1; off < 64; off <<= 1) sum += __shfl_xor(sum, off);
    if (lane == 0) red2[wave] = sum;
    __syncthreads();
    float inv = 1.f / (red2[0] + red2[1] + red2[2] + red2[3]);
    int f = *flag;
    float* pf = (float*)out + row*VV;
    u16*  pb = (u16*)out + row*VV;
    #pragma unroll
    for (int i = 0; i < 32; i++){
        int c = tid + i*256;
        if (c < VV){
            float r = v[i]*inv;
            if (f) pf[c] = r; else pb[c] = f2b(r);
        }
    }
}

// ---------------- hidden copy: ws bf16 -> d_out (bf16 or f32 per flag) ----------------
__global__ __launch_bounds__(256) void k_hidout(const u16* __restrict__ hid, void* __restrict__ out,
                                                const int* __restrict__ flag)
{
    long i = (long)blockIdx.x * 256 + threadIdx.x;   // grid 16384 -> 4,194,304
    u16 h = hid[i];
    if (*flag) ((float*)out + (size_t)M1*VV)[i] = b2f(h);
    else       ((u16*)out  + (size_t)M1*VV)[i] = h;
}

extern "C" void kernel_launch(void* const* d_in, const int* in_sizes, int n_in,
                              void* d_out, int out_size, void* d_ws, size_t ws_size,
                              hipStream_t stream)
{
    const int* pc = (const int*)d_in[1];

    const size_t MB = 1u << 20;
    char* w = (char*)d_ws;
    // ---- pipeline overlay [0, 126 MiB) ----
    u16* qin   = (u16*)(w + 0);
    u16* ctxb  = (u16*)(w + 0);
    u16* Qb    = (u16*)(w + 8*MB);
    u16* Kb    = (u16*)(w + 16*MB);
    u16* Vb    = (u16*)(w + 32*MB);
    u16* gruin = (u16*)(w + 48*MB);
    float* gi  = (float*)(w + 0);          // 48 MiB, after attn phase dead
    u16* logits= (u16*)(w + 0);            // 125 MiB, after GRU phase dead
    // ---- persistent converted inputs [126 MiB, 176 MiB) ----
    u16* enc_b = (u16*)(w + 126*MB);       // 16 MiB
    u16* emb_b = (u16*)(w + 142*MB);       // 8 MiB
    u16* pw_b  = (u16*)(w + 150*MB);       // 8 MiB
    u16* wih_b = (u16*)(w + 158*MB);       // 3 MiB
    u16* whh_b = (u16*)(w + 161*MB);       // 2 MiB
    u16* ipw_b = (u16*)(w + 163*MB);       // 2 MiB
    u16* opw_b = (u16*)(w + 165*MB);       // 1 MiB
    u16* h0_b  = (u16*)(w + 166*MB);
    u16* ipb_b = (u16*)(w + 166*MB + 128*1024);
    u16* opb_b = (u16*)(w + 166*MB + 192*1024);
    u16* bih_b = (u16*)(w + 166*MB + 256*1024);
    u16* bhh_b = (u16*)(w + 166*MB + 320*1024);
    u16* pb_b  = (u16*)(w + 166*MB + 384*1024);
    int* flag  = (int*)(w + 166*MB + 448*1024);
    float* hb0 = (float*)(w + 167*MB);
    float* hb1 = (float*)(w + 167*MB + 512*1024);
    u16* hid_b = (u16*)(w + 168*MB);       // 8 MiB

    // ---- dtype probe + input normalization to bf16 ----
    k_probe<<<1, 256, 0, stream>>>((const u16*)d_in[3], flag);
    struct { const void* s; u16* d; long n; } cv[13] = {
        { d_in[0],  enc_b, (long)M2*HH },
        { d_in[2],  h0_b,  BB*HH },
        { d_in[3],  emb_b, (long)VV*HH },
        { d_in[4],  ipw_b, 3*HH*HH },
        { d_in[5],  ipb_b, 3*HH },
        { d_in[6],  opw_b, HH*HH },
        { d_in[7],  opb_b, HH },
        { d_in[8],  wih_b, 3L*HH*2*HH },
        { d_in[9],  whh_b, 3*HH*HH },
        { d_in[10], bih_b, 3*HH },
        { d_in[11], bhh_b, 3*HH },
        { d_in[12], pw_b,  (long)VV*HH },
        { d_in[13], pb_b,  VV },
    };
    for (int i = 0; i < 13; i++){
        long n8 = cv[i].n >> 3;
        k_convert<<<(int)((n8 + 255)/256), 256, 0, stream>>>(cv[i].s, cv[i].d, flag, n8);
    }

    k_h0<<<128, 256, 0, stream>>>(h0_b, hb0);
    k_embed<<<2048, 256, 0, stream>>>(pc, emb_b, h0_b, gruin, qin);
    gemm_bt<<<dim3(64,4),  256, 0, stream>>>(qin,   HH, ipw_b,            HH, ipb_b,      Qb,  nullptr, HH,  HH, HH);
    gemm_bt<<<dim3(128,4), 256, 0, stream>>>(enc_b, HH, ipw_b + 512*512,  HH, ipb_b+512,  Kb,  nullptr, HH,  HH, HH);
    gemm_bt<<<dim3(128,4), 256, 0, stream>>>(enc_b, HH, ipw_b + 1024*512, HH, ipb_b+1024, Vb,  nullptr, HH,  HH, HH);
    k_attn<<<2048, 256, 0, stream>>>(Qb, Kb, Vb, ctxb);
    gemm_bt<<<dim3(64,4),  256, 0, stream>>>(ctxb, HH, opw_b, HH, opb_b, gruin + 512, nullptr, 2*HH, HH, HH);
    gemm_bt<<<dim3(64,12), 256, 0, stream>>>(gruin, 2*HH, wih_b, 2*HH, bih_b, nullptr, gi, 1536, 1536, 2*HH);
    for (int s = 0; s < SS; s++){
        const float* hp = (s & 1) ? hb1 : hb0;
        float* hn       = (s & 1) ? hb0 : hb1;
        k_gru_step<<<32, 256, 0, stream>>>(gi, whh_b, bhh_b, hp, hn, hid_b, s);
    }
    gemm_bt<<<dim3(64,63), 256, 0, stream>>>(hid_b, HH, pw_b, HH, pb_b, logits, nullptr, VV, VV, HH);
    k_softmax<<<M1, 256, 0, stream>>>(logits, d_out, flag);
    k_hidout<<<16384, 256, 0, stream>>>(hid_b, d_out, flag);
}